// Round 1
// baseline (119.187 us; speedup 1.0000x reference)
//
#include <hip/hip_runtime.h>
#include <math.h>

// Problem constants
#define B_ 16
#define NL_ 12
#define L1_ 197
#define D_ 768
#define E_ 4
#define K_ 3
#define C_ 21
#define IMG_ 224
#define LP_ 196   // L1 - 1 patch tokens
#define LT_ 4     // l-rows per expert block (196 = 49*4)

// ---------------------------------------------------------------------------
// Kernel 0: transpose expert_W [E][D][C] -> eWt [E][C][D] for coalesced reads
// ---------------------------------------------------------------------------
__global__ void transpose_W_kernel(const float* __restrict__ eW,
                                   float* __restrict__ eWt) {
    int ec = blockIdx.x;            // e*C + c
    int e = ec / C_, c = ec % C_;
    for (int d = threadIdx.x; d < D_; d += 256) {
        eWt[((size_t)e * C_ + c) * D_ + d] = eW[((size_t)e * D_ + d) * C_ + c];
    }
}

// ---------------------------------------------------------------------------
// Kernel 1: gate_score[b,nl,e] = cls[b,nl,:] . gate_W[:,e] + gate_b[e]
// one wave per (b,nl)
// ---------------------------------------------------------------------------
__global__ void gate_kernel(const float* __restrict__ feat,
                            const float* __restrict__ gW,
                            const float* __restrict__ gb,
                            float* __restrict__ gs) {
    int bl = blockIdx.x;                    // b*NL + nl
    int lane = threadIdx.x;                 // 0..63
    const float* cls = feat + (size_t)bl * L1_ * D_;   // token 0 of (b,nl)
    float acc0 = 0.f, acc1 = 0.f, acc2 = 0.f, acc3 = 0.f;
    for (int q = 0; q < D_ / 64; ++q) {
        int d = lane + 64 * q;
        float x = cls[d];
        float4 w = *(const float4*)(gW + (size_t)d * E_);
        acc0 += x * w.x; acc1 += x * w.y; acc2 += x * w.z; acc3 += x * w.w;
    }
    for (int off = 32; off > 0; off >>= 1) {
        acc0 += __shfl_down(acc0, off);
        acc1 += __shfl_down(acc1, off);
        acc2 += __shfl_down(acc2, off);
        acc3 += __shfl_down(acc3, off);
    }
    if (lane == 0) {
        gs[bl * E_ + 0] = acc0 + gb[0];
        gs[bl * E_ + 1] = acc1 + gb[1];
        gs[bl * E_ + 2] = acc2 + gb[2];
        gs[bl * E_ + 3] = acc3 + gb[3];
    }
}

// ---------------------------------------------------------------------------
// Kernel 2: per (b,e): softmax over NL, top-3 (ties -> lowest index),
// softmax of the top-3 probs. 64 threads total.
// ---------------------------------------------------------------------------
__global__ void select_kernel(const float* __restrict__ gs,
                              int* __restrict__ topi,
                              float* __restrict__ wgt) {
    int t = threadIdx.x;
    if (t >= B_ * E_) return;
    int b = t >> 2, e = t & 3;
    float p[NL_];
    float mx = -1e30f;
    for (int nl = 0; nl < NL_; ++nl) {
        float v = gs[(b * NL_ + nl) * E_ + e];
        p[nl] = v;
        mx = fmaxf(mx, v);
    }
    float s = 0.f;
    for (int nl = 0; nl < NL_; ++nl) { p[nl] = expf(p[nl] - mx); s += p[nl]; }
    float inv = 1.0f / s;
    for (int nl = 0; nl < NL_; ++nl) p[nl] *= inv;

    int idx[K_]; float val[K_];
    unsigned used = 0;
    for (int k = 0; k < K_; ++k) {
        float best = -1.0f; int bi = 0;
        for (int nl = 0; nl < NL_; ++nl) {
            if (!((used >> nl) & 1u) && p[nl] > best) { best = p[nl]; bi = nl; }
        }
        used |= (1u << bi);
        idx[k] = bi; val[k] = best;
    }
    // softmax over the 3 top probabilities (val[0] is the max)
    float e0 = expf(val[0] - val[0]);
    float e1 = expf(val[1] - val[0]);
    float e2 = expf(val[2] - val[0]);
    float is = 1.0f / (e0 + e1 + e2);
    int base = t * K_;
    topi[base + 0] = idx[0]; topi[base + 1] = idx[1]; topi[base + 2] = idx[2];
    wgt[base + 0] = e0 * is; wgt[base + 1] = e1 * is; wgt[base + 2] = e2 * is;
}

// ---------------------------------------------------------------------------
// Kernel 3: avg logits over experts at 14x14 resolution.
// Block = 256 thr = 4 waves; wave w handles expert e=w; LT_ l-rows per block.
//   mixed_e[l,:] = sum_k wgt[e,k] * feats[b, topi[e,k], 1+l, :]
//   avg[b,l,c]   = 0.25 * sum_e ( mixed_e[l,:] . eWt[e,c,:] + eb[e,c] )
// ---------------------------------------------------------------------------
__global__ __launch_bounds__(256) void expert_kernel(
        const float* __restrict__ feat,
        const float* __restrict__ eWt,
        const float* __restrict__ eb,
        const int* __restrict__ topi,
        const float* __restrict__ wgt,
        float* __restrict__ avg) {
    int blk = blockIdx.x;                 // b*49 + lt
    int b = blk / (LP_ / LT_);
    int l0 = (blk % (LP_ / LT_)) * LT_;
    int t = threadIdx.x;
    int lane = t & 63, e = t >> 6;

    __shared__ __align__(16) float mixed[E_][LT_][D_];   // 48 KiB
    __shared__ float outp[E_][LT_][C_];

    int base = (b * E_ + e) * K_;
    int i0 = topi[base + 0], i1 = topi[base + 1], i2 = topi[base + 2];
    float w0 = wgt[base + 0], w1 = wgt[base + 1], w2 = wgt[base + 2];
    const float* fb = feat + (size_t)b * NL_ * L1_ * D_;

    // Stage mixed rows (float4, coalesced; each wave owns its e-slice)
    for (int j = 0; j < LT_; ++j) {
        int l = l0 + j;
        const float4* r0 = (const float4*)(fb + ((size_t)i0 * L1_ + 1 + l) * D_);
        const float4* r1 = (const float4*)(fb + ((size_t)i1 * L1_ + 1 + l) * D_);
        const float4* r2 = (const float4*)(fb + ((size_t)i2 * L1_ + 1 + l) * D_);
        float4* mj = (float4*)mixed[e][j];
        for (int q = 0; q < D_ / 256; ++q) {          // 3 iters
            int d4 = lane + 64 * q;
            float4 a = r0[d4], bb = r1[d4], cc = r2[d4];
            float4 m;
            m.x = w0 * a.x + w1 * bb.x + w2 * cc.x;
            m.y = w0 * a.y + w1 * bb.y + w2 * cc.y;
            m.z = w0 * a.z + w1 * bb.z + w2 * cc.z;
            m.w = w0 * a.w + w1 * bb.w + w2 * cc.w;
            mj[d4] = m;
        }
    }
    // each wave only reads its own slice -> no barrier needed here

    const float4* Wt4 = (const float4*)(eWt + (size_t)e * C_ * D_);
    for (int c = 0; c < C_; ++c) {
        float4 wv[3];
        for (int q = 0; q < 3; ++q) wv[q] = Wt4[c * (D_ / 4) + lane + 64 * q];
        for (int j = 0; j < LT_; ++j) {
            const float4* mj = (const float4*)mixed[e][j];
            float s = 0.f;
            for (int q = 0; q < 3; ++q) {
                float4 m = mj[lane + 64 * q];
                s += m.x * wv[q].x + m.y * wv[q].y + m.z * wv[q].z + m.w * wv[q].w;
            }
            for (int off = 32; off > 0; off >>= 1) s += __shfl_down(s, off);
            if (lane == 0) outp[e][j][c] = s;
        }
    }
    __syncthreads();

    if (t < LT_ * C_) {
        int j = t / C_, c = t % C_;
        float s = 0.f;
        for (int ee = 0; ee < E_; ++ee) s += outp[ee][j][c] + eb[ee * C_ + c];
        avg[((size_t)b * LP_ + l0 + j) * C_ + c] = 0.25f * s;
    }
}

// ---------------------------------------------------------------------------
// Kernel 4: bilinear upsample 14x14 -> 224x224 (jax.image.resize semantics:
// half-pixel centers, out-of-range weight renormalization == clamp+lerp),
// layout change to [B][C][224][224]. One thread -> 4 consecutive ox (float4).
// ---------------------------------------------------------------------------
__global__ __launch_bounds__(256) void upsample_kernel(
        const float* __restrict__ avg, float* __restrict__ out) {
    const int total = B_ * C_ * IMG_ * (IMG_ / 4);     // 4,214,784
    for (int i = blockIdx.x * blockDim.x + threadIdx.x; i < total;
         i += gridDim.x * blockDim.x) {
        int ox4 = (i % (IMG_ / 4)) * 4;
        int tmp = i / (IMG_ / 4);
        int oy = tmp % IMG_; tmp /= IMG_;
        int c = tmp % C_;
        int b = tmp / C_;

        float fy = (oy + 0.5f) * 0.0625f - 0.5f;
        fy = fminf(fmaxf(fy, 0.0f), 13.0f);
        int y0 = (int)fy;
        float ty = fy - (float)y0;
        int y1 = min(y0 + 1, 13);

        const float* rowb = avg + (size_t)b * LP_ * C_ + c;
        const float* r0 = rowb + y0 * 14 * C_;
        const float* r1 = rowb + y1 * 14 * C_;

        float4 res;
        float* rp = (float*)&res;
        for (int u = 0; u < 4; ++u) {
            int ox = ox4 + u;
            float fx = (ox + 0.5f) * 0.0625f - 0.5f;
            fx = fminf(fmaxf(fx, 0.0f), 13.0f);
            int x0 = (int)fx;
            float tx = fx - (float)x0;
            int x1 = min(x0 + 1, 13);
            float v00 = r0[x0 * C_], v01 = r0[x1 * C_];
            float v10 = r1[x0 * C_], v11 = r1[x1 * C_];
            float top = v00 + tx * (v01 - v00);
            float bot = v10 + tx * (v11 - v10);
            rp[u] = top + ty * (bot - top);
        }
        ((float4*)out)[i] = res;
    }
}

// ---------------------------------------------------------------------------
extern "C" void kernel_launch(void* const* d_in, const int* in_sizes, int n_in,
                              void* d_out, int out_size, void* d_ws, size_t ws_size,
                              hipStream_t stream) {
    const float* feat = (const float*)d_in[0];   // (B, NL, 197, 768)
    const float* gW   = (const float*)d_in[1];   // (768, 4)
    const float* gb   = (const float*)d_in[2];   // (4,)
    const float* eW   = (const float*)d_in[3];   // (4, 768, 21)
    const float* eb   = (const float*)d_in[4];   // (4, 21)
    float* out = (float*)d_out;                  // (16, 21, 224, 224)

    float* ws   = (float*)d_ws;
    float* gs   = ws;                              // B*NL*E      = 768
    int*   topi = (int*)(ws + 768);                // B*E*K       = 192
    float* wgt  = ws + 768 + 192;                  // B*E*K       = 192
    float* eWt  = ws + 1152;                       // E*C*D       = 64512
    float* avg  = ws + 1152 + 64512;               // B*196*C     = 65856

    hipLaunchKernelGGL(transpose_W_kernel, dim3(E_ * C_), dim3(256), 0, stream,
                       eW, eWt);
    hipLaunchKernelGGL(gate_kernel, dim3(B_ * NL_), dim3(64), 0, stream,
                       feat, gW, gb, gs);
    hipLaunchKernelGGL(select_kernel, dim3(1), dim3(64), 0, stream,
                       gs, topi, wgt);
    hipLaunchKernelGGL(expert_kernel, dim3(B_ * (LP_ / LT_)), dim3(256), 0, stream,
                       feat, eWt, eb, topi, wgt, avg);
    hipLaunchKernelGGL(upsample_kernel, dim3(2048), dim3(256), 0, stream,
                       avg, out);
}

// Round 2
// 89.239 us; speedup vs baseline: 1.3356x; 1.3356x over previous
//
#include <hip/hip_runtime.h>
#include <math.h>

// Problem constants
#define B_ 16
#define NL_ 12
#define L1_ 197
#define D_ 768
#define E_ 4
#define K_ 3
#define C_ 21
#define IMG_ 224
#define LP_ 196   // L1 - 1 patch tokens
#define LT_ 12    // l-rows per expert block
#define NLT_ 17   // ceil(196/12)
#define RS_ 193   // LDS row stride in float4 units (192 + 1 pad -> rows 4 banks apart)

// ---------------------------------------------------------------------------
// Kernel 0: transpose expert_W [E][D][C] -> eWt [E][C][D] for vector reads
// ---------------------------------------------------------------------------
__global__ void transpose_W_kernel(const float* __restrict__ eW,
                                   float* __restrict__ eWt) {
    int ec = blockIdx.x;            // e*C + c
    int e = ec / C_, c = ec % C_;
    for (int d = threadIdx.x; d < D_; d += 256) {
        eWt[((size_t)e * C_ + c) * D_ + d] = eW[((size_t)e * D_ + d) * C_ + c];
    }
}

// ---------------------------------------------------------------------------
// Kernel 1: gate_score[b,nl,e] = cls[b,nl,:] . gate_W[:,e] + gate_b[e]
// one wave per (b,nl)
// ---------------------------------------------------------------------------
__global__ void gate_kernel(const float* __restrict__ feat,
                            const float* __restrict__ gW,
                            const float* __restrict__ gb,
                            float* __restrict__ gs) {
    int bl = blockIdx.x;                    // b*NL + nl
    int lane = threadIdx.x;                 // 0..63
    const float* cls = feat + (size_t)bl * L1_ * D_;
    float acc0 = 0.f, acc1 = 0.f, acc2 = 0.f, acc3 = 0.f;
    for (int q = 0; q < D_ / 64; ++q) {
        int d = lane + 64 * q;
        float x = cls[d];
        float4 w = *(const float4*)(gW + (size_t)d * E_);
        acc0 += x * w.x; acc1 += x * w.y; acc2 += x * w.z; acc3 += x * w.w;
    }
    for (int off = 32; off > 0; off >>= 1) {
        acc0 += __shfl_down(acc0, off);
        acc1 += __shfl_down(acc1, off);
        acc2 += __shfl_down(acc2, off);
        acc3 += __shfl_down(acc3, off);
    }
    if (lane == 0) {
        gs[bl * E_ + 0] = acc0 + gb[0];
        gs[bl * E_ + 1] = acc1 + gb[1];
        gs[bl * E_ + 2] = acc2 + gb[2];
        gs[bl * E_ + 3] = acc3 + gb[3];
    }
}

// ---------------------------------------------------------------------------
// Kernel 2: per (b,e): softmax over NL, top-3 (ties -> lowest index),
// softmax of the top-3 probs. 64 threads total.
// ---------------------------------------------------------------------------
__global__ void select_kernel(const float* __restrict__ gs,
                              int* __restrict__ topi,
                              float* __restrict__ wgt) {
    int t = threadIdx.x;
    if (t >= B_ * E_) return;
    int b = t >> 2, e = t & 3;
    float p[NL_];
    float mx = -1e30f;
    for (int nl = 0; nl < NL_; ++nl) {
        float v = gs[(b * NL_ + nl) * E_ + e];
        p[nl] = v;
        mx = fmaxf(mx, v);
    }
    float s = 0.f;
    for (int nl = 0; nl < NL_; ++nl) { p[nl] = expf(p[nl] - mx); s += p[nl]; }
    float inv = 1.0f / s;
    for (int nl = 0; nl < NL_; ++nl) p[nl] *= inv;

    int idx[K_]; float val[K_];
    unsigned used = 0;
    for (int k = 0; k < K_; ++k) {
        float best = -1.0f; int bi = 0;
        for (int nl = 0; nl < NL_; ++nl) {
            if (!((used >> nl) & 1u) && p[nl] > best) { best = p[nl]; bi = nl; }
        }
        used |= (1u << bi);
        idx[k] = bi; val[k] = best;
    }
    float e0 = expf(val[0] - val[0]);
    float e1 = expf(val[1] - val[0]);
    float e2 = expf(val[2] - val[0]);
    float is = 1.0f / (e0 + e1 + e2);
    int base = t * K_;
    topi[base + 0] = idx[0]; topi[base + 1] = idx[1]; topi[base + 2] = idx[2];
    wgt[base + 0] = e0 * is; wgt[base + 1] = e1 * is; wgt[base + 2] = e2 * is;
}

// ---------------------------------------------------------------------------
// Kernel 3 (fused mix + project + expert-mean, transposed output):
//   avgt[b][c][l] = 0.25 * sum_e ( mixed_e[l,:] . eWt[e,c,:] + eb[e,c] )
// Block = (b, tile of 12 l-rows), 256 threads.
// Per e: stage mixed rows into padded LDS (all threads, float4 coalesced),
// then thread (c = t/12, l = t%12) does a straight 192x float4 dot:
//   - LDS reads: 12 distinct rows, stride 193 float4 -> 4 banks apart (no conflict)
//   - W reads: wave-broadcast (12 lanes share one c) from pre-transposed eWt
// No shuffles, no per-iteration dependency chain -> pure ILP.
// ---------------------------------------------------------------------------
__global__ __launch_bounds__(256) void expert_kernel(
        const float* __restrict__ feat,
        const float* __restrict__ eWt,
        const float* __restrict__ eb,
        const int* __restrict__ topi,
        const float* __restrict__ wgt,
        float* __restrict__ avgt) {
    int blk = blockIdx.x;                 // b*NLT_ + lt
    int b = blk / NLT_;
    int l0 = (blk % NLT_) * LT_;
    int nrows = min(LT_, LP_ - l0);
    int t = threadIdx.x;

    __shared__ __align__(16) float4 smix[LT_ * RS_];   // ~37 KiB

    int c = t / LT_;                      // l-major lane mapping
    int l = t - c * LT_;
    bool active = (c < C_) && (l < nrows);
    float acc = 0.f;

    const float4* feat4 = (const float4*)feat;
    const float4* eWt4  = (const float4*)eWt;

    for (int e = 0; e < E_; ++e) {
        int base = (b * E_ + e) * K_;
        int i0 = topi[base + 0], i1 = topi[base + 1], i2 = topi[base + 2];
        float w0 = wgt[base + 0], w1 = wgt[base + 1], w2 = wgt[base + 2];
        // consecutive l-rows are contiguous in feat -> flat stage over nrows*192
        const float4* f0 = feat4 + ((size_t)(b * NL_ + i0) * L1_ + 1 + l0) * (D_ / 4);
        const float4* f1 = feat4 + ((size_t)(b * NL_ + i1) * L1_ + 1 + l0) * (D_ / 4);
        const float4* f2 = feat4 + ((size_t)(b * NL_ + i2) * L1_ + 1 + l0) * (D_ / 4);
        int tot = nrows * (D_ / 4);
        for (int i = t; i < tot; i += 256) {
            int r = i / (D_ / 4);
            int d4 = i - r * (D_ / 4);
            float4 a = f0[i], bb = f1[i], cc = f2[i];
            float4 m;
            m.x = w0 * a.x + w1 * bb.x + w2 * cc.x;
            m.y = w0 * a.y + w1 * bb.y + w2 * cc.y;
            m.z = w0 * a.z + w1 * bb.z + w2 * cc.z;
            m.w = w0 * a.w + w1 * bb.w + w2 * cc.w;
            smix[r * RS_ + d4] = m;
        }
        __syncthreads();
        if (active) {
            const float4* Wc   = eWt4 + (size_t)(e * C_ + c) * (D_ / 4);
            const float4* mrow = smix + l * RS_;
            float s = 0.f;
            #pragma unroll 4
            for (int d4 = 0; d4 < D_ / 4; ++d4) {
                float4 m = mrow[d4];
                float4 w = Wc[d4];
                s += m.x * w.x + m.y * w.y + m.z * w.z + m.w * w.w;
            }
            acc += s;
        }
        __syncthreads();
    }
    if (active) {
        float bias = 0.25f * (eb[c] + eb[C_ + c] + eb[2 * C_ + c] + eb[3 * C_ + c]);
        avgt[((size_t)b * C_ + c) * LP_ + l0 + l] = 0.25f * acc + bias;
    }
}

// ---------------------------------------------------------------------------
// Kernel 4: bilinear upsample 14x14 -> 224x224 from transposed avgt[b][c][196].
// Block per (b, c, row-quarter): stage the 196-float plane in LDS, each thread
// writes float4s. Write-BW bound.
// ---------------------------------------------------------------------------
__global__ __launch_bounds__(256) void upsample_kernel(
        const float* __restrict__ avgt, float* __restrict__ out) {
    int bq = blockIdx.x;
    int q  = bq & 3;          // quarter: 56 output rows
    int bc = bq >> 2;         // b*C + c
    int t = threadIdx.x;
    __shared__ float s[LP_];
    if (t < LP_) s[t] = avgt[(size_t)bc * LP_ + t];
    __syncthreads();
    float4* out4 = (float4*)out + (size_t)bc * IMG_ * (IMG_ / 4);
    for (int i = t; i < 56 * 56; i += 256) {
        int oy  = q * 56 + i / 56;
        int ox4 = (i % 56) * 4;
        float fy = (oy + 0.5f) * 0.0625f - 0.5f;
        fy = fminf(fmaxf(fy, 0.0f), 13.0f);
        int y0 = (int)fy;
        float ty = fy - (float)y0;
        int y1 = min(y0 + 1, 13);
        const float* r0 = s + y0 * 14;
        const float* r1 = s + y1 * 14;
        float4 res;
        float* rp = (float*)&res;
        for (int u = 0; u < 4; ++u) {
            int ox = ox4 + u;
            float fx = (ox + 0.5f) * 0.0625f - 0.5f;
            fx = fminf(fmaxf(fx, 0.0f), 13.0f);
            int x0 = (int)fx;
            float tx = fx - (float)x0;
            int x1 = min(x0 + 1, 13);
            float v00 = r0[x0], v01 = r0[x1];
            float v10 = r1[x0], v11 = r1[x1];
            float top = v00 + tx * (v01 - v00);
            float bot = v10 + tx * (v11 - v10);
            rp[u] = top + ty * (bot - top);
        }
        out4[oy * 56 + (i % 56)] = res;
    }
}

// ---------------------------------------------------------------------------
extern "C" void kernel_launch(void* const* d_in, const int* in_sizes, int n_in,
                              void* d_out, int out_size, void* d_ws, size_t ws_size,
                              hipStream_t stream) {
    const float* feat = (const float*)d_in[0];   // (B, NL, 197, 768)
    const float* gW   = (const float*)d_in[1];   // (768, 4)
    const float* gb   = (const float*)d_in[2];   // (4,)
    const float* eW   = (const float*)d_in[3];   // (4, 768, 21)
    const float* eb   = (const float*)d_in[4];   // (4, 21)
    float* out = (float*)d_out;                  // (16, 21, 224, 224)

    float* ws   = (float*)d_ws;
    float* gs   = ws;                              // B*NL*E      = 768
    int*   topi = (int*)(ws + 768);                // B*E*K       = 192
    float* wgt  = ws + 768 + 192;                  // B*E*K       = 192
    float* eWt  = ws + 1152;                       // E*C*D       = 64512
    float* avgt = ws + 1152 + 64512;               // B*C*196     = 65856

    hipLaunchKernelGGL(transpose_W_kernel, dim3(E_ * C_), dim3(256), 0, stream,
                       eW, eWt);
    hipLaunchKernelGGL(gate_kernel, dim3(B_ * NL_), dim3(64), 0, stream,
                       feat, gW, gb, gs);
    hipLaunchKernelGGL(select_kernel, dim3(1), dim3(64), 0, stream,
                       gs, topi, wgt);
    hipLaunchKernelGGL(expert_kernel, dim3(B_ * NLT_), dim3(256), 0, stream,
                       feat, eWt, eb, topi, wgt, avgt);
    hipLaunchKernelGGL(upsample_kernel, dim3(B_ * C_ * 4), dim3(256), 0, stream,
                       avgt, out);
}